// Round 2
// baseline (144.576 us; speedup 1.0000x reference)
//
#include <hip/hip_runtime.h>
#include <cstdint>
#include <cstddef>

// Problem constants (F, H, D, A, B) = (500, 2000, 64, 64, 4096)
#define F_N 500
#define H_N 2000
#define JN  2500   // F + H
#define D_N 64
#define A_N 64
#define B_N 4096

// ---------------------------------------------------------------------------
// Kernel 1: pre_f[i][a] = feat[i,:] @ W1[:,a] + bw[a]   (row-major, 500x64)
//           pre_wT[a][j] = full[j,:] @ W2[:,a]          (TRANSPOSED, 64x2500)
// full[j] = j < 500 ? feat[j] : hid[j-500]
// 48 blocks x 1024 threads (16 waves). Each wave computes 4 rows (4
// independent fma chains sharing one W column-load per d; full unroll ->
// v_readlane with immediate lane, no LDS-pipe shfl latency).
// Blocks 0..7: pre_f (64 rows each, direct coalesced store).
// Blocks 8..47: pre_w (64 rows each, LDS 64x65 tile -> coalesced transposed
// store into pre_wT).
// ---------------------------------------------------------------------------
__global__ __launch_bounds__(1024) void k_pre(
    const float* __restrict__ feat, const float* __restrict__ hid,
    const float* __restrict__ Ww,   const float* __restrict__ bw,
    float* __restrict__ pre_f, float* __restrict__ pre_wT)
{
    const int lane = threadIdx.x & 63;
    const int wave = threadIdx.x >> 6;

    __shared__ float tile[64 * 65];

    const bool isPreF = (blockIdx.x < 8);
    const int  rbase  = isPreF ? blockIdx.x * 64 : (blockIdx.x - 8) * 64;
    const int  r0     = rbase + wave * 4;          // first of this wave's 4 rows
    const int  rowLim = isPreF ? F_N : JN;

    const float* W = isPreF ? Ww : (Ww + D_N * A_N);

    float acc0, acc1, acc2, acc3;
    if (isPreF) { const float b = bw[lane]; acc0 = acc1 = acc2 = acc3 = b; }
    else        { acc0 = acc1 = acc2 = acc3 = 0.0f; }

    // per-row embedding element held in lane (lane indexes d)
    float e0 = 0.f, e1 = 0.f, e2 = 0.f, e3 = 0.f;
    {
        const int r[4] = { r0, r0 + 1, r0 + 2, r0 + 3 };
        float* ep[4] = { &e0, &e1, &e2, &e3 };
        #pragma unroll
        for (int q = 0; q < 4; ++q) {
            const int rr = r[q];
            if (rr < rowLim) {
                const float* emb;
                if (isPreF)          emb = feat + (size_t)rr * D_N;
                else if (rr < F_N)   emb = feat + (size_t)rr * D_N;
                else                 emb = hid + (size_t)(rr - F_N) * D_N;
                *ep[q] = emb[lane];
            }
        }
    }

    #pragma unroll
    for (int d = 0; d < D_N; ++d) {
        const float w = W[d * A_N + lane];      // coalesced, L2-hot (16 KB)
        acc0 = fmaf(__shfl(e0, d, 64), w, acc0);
        acc1 = fmaf(__shfl(e1, d, 64), w, acc1);
        acc2 = fmaf(__shfl(e2, d, 64), w, acc2);
        acc3 = fmaf(__shfl(e3, d, 64), w, acc3);
    }

    if (isPreF) {
        if (r0 + 0 < F_N) pre_f[(size_t)(r0 + 0) * A_N + lane] = acc0;
        if (r0 + 1 < F_N) pre_f[(size_t)(r0 + 1) * A_N + lane] = acc1;
        if (r0 + 2 < F_N) pre_f[(size_t)(r0 + 2) * A_N + lane] = acc2;
        if (r0 + 3 < F_N) pre_f[(size_t)(r0 + 3) * A_N + lane] = acc3;
    } else {
        const int l0 = wave * 4;
        tile[(l0 + 0) * 65 + lane] = acc0;
        tile[(l0 + 1) * 65 + lane] = acc1;
        tile[(l0 + 2) * 65 + lane] = acc2;
        tile[(l0 + 3) * 65 + lane] = acc3;
        __syncthreads();
        // write out transposed: pre_wT[a][rbase + jj] = tile[jj][a]
        #pragma unroll
        for (int k = 0; k < 4; ++k) {
            const int idx = threadIdx.x + k * 1024;   // 0..4095
            const int a   = idx >> 6;
            const int jj  = idx & 63;
            const int j   = rbase + jj;
            if (j < JN)
                pre_wT[(size_t)a * JN + j] = tile[jj * 65 + a];
        }
    }
}

// ---------------------------------------------------------------------------
// Kernel 2: per i (block = one i, 256 threads, 4 waves):
//   A) compact active j's (mask[i][j] != 0) into LDS list (ballot+rank+atomic)
//   B) each THREAD owns one active j: s_j = sum_a Wu[a]*tanh(pf[a]+pre_wT[a][j])
//      -> e_j = exp(s_j). No cross-lane ops; pre_wT gather is L2-resident.
//   C) context: waves stride the active list (wave-uniform idx), coalesced
//      full[j] row loads, lane = d; combine + normalize.
// ---------------------------------------------------------------------------
__global__ __launch_bounds__(256) void k_attn(
    const float* __restrict__ feat, const float* __restrict__ hid,
    const float* __restrict__ pre_f, const float* __restrict__ pre_wT,
    const float* __restrict__ Wu,   const void* __restrict__ mask,
    float* __restrict__ ctx)
{
    const int tid  = threadIdx.x;
    const int lane = tid & 63;
    const int wave = tid >> 6;
    const int i    = blockIdx.x;

    __shared__ int   list[JN];
    __shared__ float earr[JN];
    __shared__ float s_ctx[4][64];
    __shared__ int   nact;

    if (tid == 0) nact = 0;
    __syncthreads();

    // --- runtime mask-dtype detection: bool bytes vs int32 -----------------
    const uint32_t* mw = (const uint32_t*)mask;
    const uint32_t probe = mw[lane] | mw[64 + lane] | mw[128 + lane] | mw[192 + lane];
    const bool byteMode = (__ballot(probe > 1u) != 0ull);

    const uint8_t*  mb = (const uint8_t*)mask + (size_t)i * JN;
    const uint32_t* mi = (const uint32_t*)mask + (size_t)i * JN;

    // --- A: compaction ------------------------------------------------------
    for (int t = tid; t < 2560; t += 256) {            // 10 uniform passes
        uint32_t m = 0;
        if (t < JN) m = byteMode ? (uint32_t)mb[t] : mi[t];
        const unsigned long long act = __ballot(m != 0);
        const int cnt = __popcll(act);
        int base = 0;
        if (lane == 0 && cnt) base = atomicAdd(&nact, cnt);
        base = __shfl(base, 0, 64);
        if (m) {
            const int rank = __popcll(act & ((1ull << lane) - 1ull));
            list[base + rank] = t;
        }
    }
    __syncthreads();
    const int n = nact;

    // --- B: per-thread score for one active j -------------------------------
    const float* pf = pre_f + (size_t)i * A_N;   // wave-uniform -> s_loads
    for (int idx = tid; idx < n; idx += 256) {
        const int j = list[idx];
        float s = 0.0f;
        #pragma unroll 8
        for (int a = 0; a < A_N; ++a) {
            const float x = pf[a] + pre_wT[(size_t)a * JN + j];  // gather, L2
            const float t = 1.0f - 2.0f / (__expf(2.0f * x) + 1.0f);
            s = fmaf(Wu[a], t, s);
        }
        earr[idx] = __expf(s);
    }
    __syncthreads();

    // --- C: context accumulation (lane = d) ---------------------------------
    float cacc = 0.0f;
    for (int idx = wave; idx < n; idx += 4) {          // wave-uniform idx
        const float e = earr[idx];                     // LDS broadcast
        const int   j = list[idx];
        const float* row = (j < F_N) ? (feat + (size_t)j * D_N)
                                     : (hid + (size_t)(j - F_N) * D_N);
        cacc = fmaf(e, row[lane], cacc);
    }
    s_ctx[wave][lane] = cacc;
    __syncthreads();

    if (wave == 0) {
        const float c4 = s_ctx[0][lane] + s_ctx[1][lane] + s_ctx[2][lane] + s_ctx[3][lane];
        float ss = 0.0f;
        for (int k = lane; k < n; k += 64) ss += earr[k];
        #pragma unroll
        for (int off = 1; off < 64; off <<= 1) ss += __shfl_xor(ss, off, 64);
        if (ss == 0.0f) ss = 1.0f;                     // reference semantics
        ctx[(size_t)i * D_N + lane] = c4 / ss;
    }
}

// ---------------------------------------------------------------------------
// Kernel 3: out = values (4096x500) @ ctx (500x64), f32 VALU.
// 512 blocks x 256 threads; block handles 8 rows (2 rows per wave), lane = d.
// ctx staged in LDS in 100-k chunks; values rows read as float4.
// ---------------------------------------------------------------------------
__global__ __launch_bounds__(256) void k_out(
    const float* __restrict__ values, const float* __restrict__ ctx,
    float* __restrict__ out)
{
    const int lane = threadIdx.x & 63;
    const int wave = threadIdx.x >> 6;
    const int row0 = blockIdx.x * 8 + wave * 2;

    __shared__ float lds[100 * 64];
    float acc0 = 0.0f, acc1 = 0.0f;

    for (int chunk = 0; chunk < 5; ++chunk) {
        const int k0 = chunk * 100;
        __syncthreads();
        for (int t = threadIdx.x; t < 100 * 64; t += 256)
            lds[t] = ctx[(size_t)k0 * 64 + t];
        __syncthreads();

        const float* v0p = values + (size_t)row0 * 500 + k0;
        const float* v1p = v0p + 500;
        #pragma unroll 5
        for (int kc = 0; kc < 100; kc += 4) {
            const float4 a = *(const float4*)(v0p + kc);
            const float4 b = *(const float4*)(v1p + kc);
            const float l0 = lds[(kc + 0) * 64 + lane];
            const float l1 = lds[(kc + 1) * 64 + lane];
            const float l2 = lds[(kc + 2) * 64 + lane];
            const float l3 = lds[(kc + 3) * 64 + lane];
            acc0 = fmaf(a.x, l0, acc0); acc0 = fmaf(a.y, l1, acc0);
            acc0 = fmaf(a.z, l2, acc0); acc0 = fmaf(a.w, l3, acc0);
            acc1 = fmaf(b.x, l0, acc1); acc1 = fmaf(b.y, l1, acc1);
            acc1 = fmaf(b.z, l2, acc1); acc1 = fmaf(b.w, l3, acc1);
        }
    }
    out[(size_t)row0 * 64 + lane]       = acc0;
    out[(size_t)(row0 + 1) * 64 + lane] = acc1;
}

// ---------------------------------------------------------------------------
extern "C" void kernel_launch(void* const* d_in, const int* in_sizes, int n_in,
                              void* d_out, int out_size, void* d_ws, size_t ws_size,
                              hipStream_t stream)
{
    const float* values = (const float*)d_in[0];   // (4096, 500)
    const float* feat   = (const float*)d_in[1];   // (500, 64)
    const float* hid    = (const float*)d_in[2];   // (2000, 64)
    const float* Ww     = (const float*)d_in[3];   // (128, 64)
    const float* bw     = (const float*)d_in[4];   // (64,)
    const float* Wu     = (const float*)d_in[5];   // (64, 1)
    const void*  mask   = d_in[6];                 // (500, 2500, 1) — dtype detected on device
    float* out = (float*)d_out;                    // (4096, 64)

    // Workspace layout (floats): pre_f[500*64] | pre_wT[64*2500] | ctx[500*64]
    float* wsf    = (float*)d_ws;
    float* pre_f  = wsf;                  // 32000 floats
    float* pre_wT = wsf + 32000;          // 160000 floats (transposed 64 x 2500)
    float* ctx    = wsf + 192000;         // 32000 floats

    k_pre <<<48, 1024, 0, stream>>>(feat, hid, Ww, bw, pre_f, pre_wT);
    k_attn<<<500, 256, 0, stream>>>(feat, hid, pre_f, pre_wT, Wu, mask, ctx);
    k_out <<<512, 256, 0, stream>>>(values, ctx, out);
}

// Round 3
// 132.166 us; speedup vs baseline: 1.0939x; 1.0939x over previous
//
#include <hip/hip_runtime.h>
#include <cstdint>
#include <cstddef>

// Problem constants (F, H, D, A, B) = (500, 2000, 64, 64, 4096)
#define F_N 500
#define H_N 2000
#define JN  2500   // F + H
#define D_N 64
#define A_N 64
#define B_N 4096

// ---------------------------------------------------------------------------
// Kernel 1: pre_f[i][a] = feat[i,:] @ W1[:,a] + bw[a]   (row-major, 500x64)
//           pre_w[j][a] = full[j,:] @ W2[:,a]           (row-major, 2500x64)
// full[j] = j < 500 ? feat[j] : hid[j-500]
// One wave per output row; lane = a. 750 blocks x 256 threads (all CUs busy;
// R2's 48x1024 variant left 208 CUs idle).
// ---------------------------------------------------------------------------
__global__ __launch_bounds__(256) void k_pre(
    const float* __restrict__ feat, const float* __restrict__ hid,
    const float* __restrict__ Ww,   const float* __restrict__ bw,
    float* __restrict__ pre_f, float* __restrict__ pre_w)
{
    const int lane = threadIdx.x & 63;
    const int wave = threadIdx.x >> 6;
    const int row  = blockIdx.x * 4 + wave;       // 0..2999
    if (row >= F_N + JN) return;

    const float* emb;
    const float* W;
    float*       outp;
    float        acc = 0.0f;

    if (row < F_N) {                 // pre_f row (bias folded in)
        emb  = feat + (size_t)row * D_N;
        W    = Ww;                   // W1 = Ww[0:64]
        outp = pre_f + (size_t)row * A_N;
        acc  = bw[lane];
    } else {                         // pre_w row
        const int j = row - F_N;
        emb  = (j < F_N) ? (feat + (size_t)j * D_N)
                         : (hid + (size_t)(j - F_N) * D_N);
        W    = Ww + D_N * A_N;       // W2 = Ww[64:128]
        outp = pre_w + (size_t)j * A_N;
    }

    const float e = emb[lane];       // emb[row][lane]; broadcast via shfl
    #pragma unroll
    for (int d = 0; d < D_N; ++d) {
        const float w = W[d * A_N + lane];   // coalesced, L2-hot (16 KB)
        acc = fmaf(__shfl(e, d, 64), w, acc);
    }
    outp[lane] = acc;                // coalesced row-major store
}

// ---------------------------------------------------------------------------
// Kernel 2: per i (block = one i, 256 threads, 4 waves):
//   A) compact active j's (mask[i][j] != 0) into LDS list (ballot+rank+atomic)
//   B) thread owns one active j, loops a over ROW-MAJOR pre_w[j][a] as float4.
//      First float4 pulls the lane's whole 256 B row; the wave's 64 active
//      rows = 16 KB -> L1-resident for the remaining 15 steps. pre_f[i][.]
//      and Wu are block-uniform -> s_loads. No cross-lane ops.
//   C) context: waves stride the active list (wave-uniform idx), coalesced
//      full[j] row loads, lane = d; combine + normalize.
// ---------------------------------------------------------------------------
__global__ __launch_bounds__(256) void k_attn(
    const float* __restrict__ feat, const float* __restrict__ hid,
    const float* __restrict__ pre_f, const float* __restrict__ pre_w,
    const float* __restrict__ Wu,   const void* __restrict__ mask,
    float* __restrict__ ctx)
{
    const int tid  = threadIdx.x;
    const int lane = tid & 63;
    const int wave = tid >> 6;
    const int i    = blockIdx.x;

    __shared__ int   list[JN];
    __shared__ float earr[JN];
    __shared__ float s_ctx[4][64];
    __shared__ int   nact;

    if (tid == 0) nact = 0;
    __syncthreads();

    // --- runtime mask-dtype detection: bool bytes vs int32 -----------------
    // int32 0/1 -> every u32 word <= 1; byte-packed bools -> some word of the
    // first 256 exceeds 1 w.p. ~1 - 0.73^256.
    const uint32_t* mw = (const uint32_t*)mask;
    const uint32_t probe = mw[lane] | mw[64 + lane] | mw[128 + lane] | mw[192 + lane];
    const bool byteMode = (__ballot(probe > 1u) != 0ull);

    const uint8_t*  mb = (const uint8_t*)mask + (size_t)i * JN;
    const uint32_t* mi = (const uint32_t*)mask + (size_t)i * JN;

    // --- A: compaction ------------------------------------------------------
    for (int t = tid; t < 2560; t += 256) {            // 10 uniform passes
        uint32_t m = 0;
        if (t < JN) m = byteMode ? (uint32_t)mb[t] : mi[t];
        const unsigned long long act = __ballot(m != 0);
        const int cnt = __popcll(act);
        int base = 0;
        if (lane == 0 && cnt) base = atomicAdd(&nact, cnt);
        base = __shfl(base, 0, 64);
        if (m) {
            const int rank = __popcll(act & ((1ull << lane) - 1ull));
            list[base + rank] = t;
        }
    }
    __syncthreads();
    const int n = nact;

    // --- B: per-thread score for one active j (row-major, L1-resident) -----
    const float* pf = pre_f + (size_t)i * A_N;   // block-uniform -> s_loads
    for (int idx = tid; idx < n; idx += 256) {
        const int j = list[idx];
        const float4* pwj = (const float4*)(pre_w + (size_t)j * A_N); // 256B-aligned
        float s = 0.0f;
        #pragma unroll
        for (int q = 0; q < 16; ++q) {
            const float4 v = pwj[q];
            const int a = q * 4;
            // tanh(x) = 1 - 2/(exp(2x)+1); safe for all x
            const float x0 = pf[a + 0] + v.x;
            const float x1 = pf[a + 1] + v.y;
            const float x2 = pf[a + 2] + v.z;
            const float x3 = pf[a + 3] + v.w;
            const float t0 = 1.0f - 2.0f / (__expf(2.0f * x0) + 1.0f);
            const float t1 = 1.0f - 2.0f / (__expf(2.0f * x1) + 1.0f);
            const float t2 = 1.0f - 2.0f / (__expf(2.0f * x2) + 1.0f);
            const float t3 = 1.0f - 2.0f / (__expf(2.0f * x3) + 1.0f);
            s = fmaf(Wu[a + 0], t0, s);
            s = fmaf(Wu[a + 1], t1, s);
            s = fmaf(Wu[a + 2], t2, s);
            s = fmaf(Wu[a + 3], t3, s);
        }
        earr[idx] = __expf(s);
    }
    __syncthreads();

    // --- C: context accumulation (lane = d) ---------------------------------
    float cacc = 0.0f;
    for (int idx = wave; idx < n; idx += 4) {          // wave-uniform idx
        const float e = earr[idx];                     // LDS broadcast
        const int   j = list[idx];
        const float* row = (j < F_N) ? (feat + (size_t)j * D_N)
                                     : (hid + (size_t)(j - F_N) * D_N);
        cacc = fmaf(e, row[lane], cacc);
    }
    s_ctx[wave][lane] = cacc;
    __syncthreads();

    if (wave == 0) {
        const float c4 = s_ctx[0][lane] + s_ctx[1][lane] + s_ctx[2][lane] + s_ctx[3][lane];
        float ss = 0.0f;
        for (int k = lane; k < n; k += 64) ss += earr[k];
        #pragma unroll
        for (int off = 1; off < 64; off <<= 1) ss += __shfl_xor(ss, off, 64);
        if (ss == 0.0f) ss = 1.0f;                     // reference semantics
        ctx[(size_t)i * D_N + lane] = c4 / ss;
    }
}

// ---------------------------------------------------------------------------
// Kernel 3: out = values (4096x500) @ ctx (500x64), f32 VALU.
// 512 blocks x 256 threads; block handles 8 rows (2 rows per wave), lane = d.
// ctx staged in LDS in 100-k chunks; values rows read as float4
// (row stride 2000 B and chunk offset 400 B are 16B-aligned).
// ---------------------------------------------------------------------------
__global__ __launch_bounds__(256) void k_out(
    const float* __restrict__ values, const float* __restrict__ ctx,
    float* __restrict__ out)
{
    const int lane = threadIdx.x & 63;
    const int wave = threadIdx.x >> 6;
    const int row0 = blockIdx.x * 8 + wave * 2;

    __shared__ float lds[100 * 64];
    float acc0 = 0.0f, acc1 = 0.0f;

    for (int chunk = 0; chunk < 5; ++chunk) {
        const int k0 = chunk * 100;
        __syncthreads();
        for (int t = threadIdx.x; t < 100 * 64; t += 256)
            lds[t] = ctx[(size_t)k0 * 64 + t];
        __syncthreads();

        const float* v0p = values + (size_t)row0 * 500 + k0;
        const float* v1p = v0p + 500;
        #pragma unroll 5
        for (int kc = 0; kc < 100; kc += 4) {
            const float4 a = *(const float4*)(v0p + kc);
            const float4 b = *(const float4*)(v1p + kc);
            const float l0 = lds[(kc + 0) * 64 + lane];
            const float l1 = lds[(kc + 1) * 64 + lane];
            const float l2 = lds[(kc + 2) * 64 + lane];
            const float l3 = lds[(kc + 3) * 64 + lane];
            acc0 = fmaf(a.x, l0, acc0); acc0 = fmaf(a.y, l1, acc0);
            acc0 = fmaf(a.z, l2, acc0); acc0 = fmaf(a.w, l3, acc0);
            acc1 = fmaf(b.x, l0, acc1); acc1 = fmaf(b.y, l1, acc1);
            acc1 = fmaf(b.z, l2, acc1); acc1 = fmaf(b.w, l3, acc1);
        }
    }
    out[(size_t)row0 * 64 + lane]       = acc0;
    out[(size_t)(row0 + 1) * 64 + lane] = acc1;
}

// ---------------------------------------------------------------------------
extern "C" void kernel_launch(void* const* d_in, const int* in_sizes, int n_in,
                              void* d_out, int out_size, void* d_ws, size_t ws_size,
                              hipStream_t stream)
{
    const float* values = (const float*)d_in[0];   // (4096, 500)
    const float* feat   = (const float*)d_in[1];   // (500, 64)
    const float* hid    = (const float*)d_in[2];   // (2000, 64)
    const float* Ww     = (const float*)d_in[3];   // (128, 64)
    const float* bw     = (const float*)d_in[4];   // (64,)
    const float* Wu     = (const float*)d_in[5];   // (64, 1)
    const void*  mask   = d_in[6];                 // (500, 2500, 1) — dtype detected on device
    float* out = (float*)d_out;                    // (4096, 64)

    // Workspace layout (floats): pre_f[500*64] | pre_w[2500*64] | ctx[500*64]
    float* wsf   = (float*)d_ws;
    float* pre_f = wsf;                  // 32000 floats
    float* pre_w = wsf + 32000;          // 160000 floats (row-major 2500 x 64)
    float* ctx   = wsf + 192000;         // 32000 floats

    k_pre <<<750, 256, 0, stream>>>(feat, hid, Ww, bw, pre_f, pre_w);
    k_attn<<<500, 256, 0, stream>>>(feat, hid, pre_f, pre_w, Wu, mask, ctx);
    k_out <<<512, 256, 0, stream>>>(values, ctx, out);
}